// Round 3
// baseline (934.399 us; speedup 1.0000x reference)
//
#include <hip/hip_runtime.h>

// Volume geometry (static per reference): [D=128, H=160, W=128], fp32
constexpr int DD = 128, HH = 160, WW = 128;
constexpr int ZSTR = HH * WW;              // 20480
constexpr long long NV = (long long)DD * HH * WW;   // 2621440
constexpr long long VOLB = NV * 4;         // 10485760 bytes
constexpr int RAD = 20, NTAP = 41;

__device__ __forceinline__ int lutmap(int v) {
    // LUT = [0..19] + [1..10, 14..19]
    return v < 20 ? v : (v < 30 ? v - 19 : v - 16);
}

// acc[p] += sum_k w[k] * win[k+p]  (out position p; tap offset k-20)
__device__ __forceinline__ void taps(const float* win, const float* __restrict__ w,
                                     float acc[8]) {
#pragma unroll
    for (int k = 0; k < NTAP; ++k) {
        float wk = w[k];
#pragma unroll
        for (int p = 0; p < 8; ++p) acc[p] = fmaf(wk, win[k + p], acc[p]);
    }
}

// ---------------- prep: val = mu[c] + std[c]*noise[c][i]; cls = c -------------
__global__ __launch_bounds__(256) void kprep(const int* __restrict__ x,
                                             const float* __restrict__ noise,
                                             const float* __restrict__ mus,
                                             const float* __restrict__ stds,
                                             float* __restrict__ val,
                                             unsigned char* __restrict__ cls) {
    long long i = (long long)blockIdx.x * 256 + threadIdx.x;
    int c = lutmap(x[i]);
    val[i] = mus[c] + stds[c] * noise[(long long)c * NV + i];
    cls[i] = (unsigned char)c;
}

// ---------------- weights: wts[c][0..40] normalized over all 41 taps ----------
__global__ void kweights(const float* __restrict__ gsig, const float* __restrict__ fsig,
                         float* __restrict__ wts) {
    int c = threadIdx.x;
    if (c > 20) return;
    float sigma = (c < 20) ? gsig[c] : fsig[0];
    float inv = 1.0f / sigma;
    float buf[NTAP];
    float s = 0.f;
    for (int k = 0; k < NTAP; ++k) {
        float d = (float)(k - RAD) * inv;
        buf[k] = expf(-0.5f * d * d);
        s += buf[k];
    }
    float r = 1.0f / s;
    for (int k = 0; k < NTAP; ++k) wts[c * NTAP + k] = buf[k] * r;
}

// ---------------- fused X+Y smooth for one z-slice, one class -----------------
// Tile: full height 160 x 32 outputs in x, 20-halo each side in LDS.
// LDS plane stride padded to 76 to spread banks on the conv-x window reads.
template <bool MASKED>
__global__ __launch_bounds__(256) void ksmooth_xy(const float* __restrict__ src,
                                                  const unsigned char* __restrict__ cls,
                                                  const float* __restrict__ wts,
                                                  float* __restrict__ dst, int c0) {
    constexpr int AW = 76;  // 72 used cols, padded
    __shared__ float A[HH * AW];  // 48640 B

    const int x0 = blockIdx.x * 32;
    const int z = blockIdx.y;
    const int c = MASKED ? (c0 + blockIdx.z) : 20;
    const float* w = wts + c * NTAP;
    const long long zbase = (long long)z * ZSTR;

    // field load (with x zero-pad halo)
    for (int l = threadIdx.x; l < HH * 72; l += 256) {
        int yy = l / 72, xx = l - yy * 72;
        int gx = x0 - RAD + xx;
        float v = 0.f;
        if ((unsigned)gx < (unsigned)WW) {
            long long idx = zbase + yy * WW + gx;
            if (MASKED) {
                if (cls[idx] == (unsigned char)c) v = src[idx];
            } else {
                v = src[idx];
            }
        }
        A[yy * AW + xx] = v;
    }
    __syncthreads();

    // conv-x in place: writes only cols [20,52); halo cols untouched
    {
        const int m = threadIdx.x & 3;   // x sub-block (8 outputs)
        const int q = threadIdx.x >> 2;  // row within pass
        const int xb = m * 8;
        for (int pass = 0; pass < 3; ++pass) {
            int y = pass * 64 + q;
            float acc[8] = {0, 0, 0, 0, 0, 0, 0, 0};
            if (y < HH) {
                float win[NTAP + 7];
                const float* row = &A[y * AW + xb];  // win[j] = A[y][xb+j]
#pragma unroll
                for (int j = 0; j < NTAP + 7; ++j) win[j] = row[j];
                taps(win, w, acc);
            }
            __syncthreads();
            if (y < HH) {
#pragma unroll
                for (int p = 0; p < 8; ++p) A[y * AW + RAD + xb + p] = acc[p];
            }
            __syncthreads();
        }
    }

    // conv-y (y zero-pad), write to global
    {
        const int x = threadIdx.x & 31;
        const int yg = threadIdx.x >> 5;
        const long long obase =
            MASKED ? ((long long)blockIdx.z * DD + z) * ZSTR : zbase;
        for (int pass = 0; pass < 3; ++pass) {
            int yb = pass * 64 + yg * 8;
            if (yb < HH) {
                float win[NTAP + 7];
#pragma unroll
                for (int j = 0; j < NTAP + 7; ++j) {
                    int ry = yb - RAD + j;
                    win[j] = ((unsigned)ry < (unsigned)HH) ? A[ry * AW + RAD + x] : 0.f;
                }
                float acc[8] = {0, 0, 0, 0, 0, 0, 0, 0};
                taps(win, w, acc);
#pragma unroll
                for (int p = 0; p < 8; ++p)
                    dst[obase + (long long)(yb + p) * WW + x0 + x] = acc[p];
            }
        }
    }
}

// ---------------- Z smooth; accumulates over nc classes -----------------------
// Tile: 64 z-outputs x 32 x at fixed y; 20-halo in z.
template <bool ACCUM>
__global__ __launch_bounds__(256) void ksmooth_z(const float* __restrict__ src,
                                                 const float* __restrict__ wts,
                                                 float* __restrict__ out, int c0,
                                                 int nc) {
    constexpr int LW = 33;
    __shared__ float L[104 * LW];  // 13728 B

    const int x0 = blockIdx.x * 32;
    const int z0 = blockIdx.y * 64;
    const int y = blockIdx.z;
    const int x = threadIdx.x & 31;
    const int tg = threadIdx.x >> 5;

    float acc[8] = {0, 0, 0, 0, 0, 0, 0, 0};
    for (int cc = 0; cc < nc; ++cc) {
        const float* w = wts + (ACCUM ? (c0 + cc) : 20) * NTAP;
        const float* sv = src + (long long)cc * NV;
        for (int t = tg; t < 104; t += 8) {
            int gz = z0 - RAD + t;
            float v = ((unsigned)gz < (unsigned)DD)
                          ? sv[(long long)gz * ZSTR + y * WW + x0 + x]
                          : 0.f;
            L[t * LW + x] = v;
        }
        __syncthreads();
        {
            const int zb = tg * 8;
            float win[NTAP + 7];
#pragma unroll
            for (int j = 0; j < NTAP + 7; ++j) win[j] = L[(zb + j) * LW + x];
            taps(win, w, acc);
        }
        __syncthreads();
    }
    const int zb = tg * 8;
#pragma unroll
    for (int p = 0; p < 8; ++p) {
        long long o = (long long)(z0 + zb + p) * ZSTR + y * WW + x0 + x;
        if (ACCUM)
            out[o] += acc[p];
        else
            out[o] = acc[p];
    }
}

extern "C" void kernel_launch(void* const* d_in, const int* in_sizes, int n_in,
                              void* d_out, int out_size, void* d_ws, size_t ws_size,
                              hipStream_t stream) {
    const int* x = (const int*)d_in[0];
    const float* noise = (const float*)d_in[1];
    const float* mus = (const float*)d_in[2];
    const float* stds = (const float*)d_in[3];
    const float* gsig = (const float*)d_in[4];
    const float* fsig = (const float*)d_in[5];
    float* out = (float*)d_out;

    char* ws = (char*)d_ws;
    size_t off = 0;
    float* wts = (float*)(ws + off);
    off += 4096;
    float* val = (float*)(ws + off);
    off += (size_t)VOLB;
    unsigned char* cls = (unsigned char*)(ws + off);
    off += (size_t)NV;  // multiple of 256
    float* ftmp = (float*)(ws + off);
    off += (size_t)VOLB;
    float* xy = (float*)(ws + off);

    long long cap = ((long long)ws_size - (long long)off) / VOLB;
    int C = cap < 1 ? 1 : (cap > 20 ? 20 : (int)cap);  // class chunk size

    kweights<<<1, 64, 0, stream>>>(gsig, fsig, wts);
    kprep<<<(int)(NV / 256), 256, 0, stream>>>(x, noise, mus, stds, val, cls);
    hipMemsetAsync(d_out, 0, (size_t)VOLB, stream);

    for (int c0 = 0; c0 < 20; c0 += C) {
        int cc = (20 - c0) < C ? (20 - c0) : C;
        ksmooth_xy<true><<<dim3(4, DD, cc), 256, 0, stream>>>(val, cls, wts, xy, c0);
        ksmooth_z<true><<<dim3(4, 2, HH), 256, 0, stream>>>(xy, wts, out, c0, cc);
    }
    // final smooth: summed (in d_out) -> XY -> ftmp -> Z -> d_out
    ksmooth_xy<false><<<dim3(4, DD, 1), 256, 0, stream>>>(out, nullptr, wts, ftmp, 0);
    ksmooth_z<false><<<dim3(4, 2, HH), 256, 0, stream>>>(ftmp, wts, out, 0, 1);
}

// Round 5
// 572.378 us; speedup vs baseline: 1.6325x; 1.6325x over previous
//
#include <hip/hip_runtime.h>

// Volume geometry (static per reference): [D=128, H=160, W=128], fp32
constexpr int DD = 128, HH = 160, WW = 128;
constexpr int ZSTR = HH * WW;              // 20480
constexpr long long NV = (long long)DD * HH * WW;   // 2621440
constexpr long long VOLB = NV * 4;         // 10485760 bytes
constexpr int RAD = 20, NTAP = 41;
// x-padded layout: [z][y][xp], xp = 24 zero | 128 data | 24 zero
constexpr int PW = 176;
constexpr int PADC = 24;
constexpr long long NVP = (long long)DD * HH * PW;  // 3604480

__device__ __forceinline__ int lutmap(int v) {
    // LUT = [0..19] + [1..10, 14..19]
    return v < 20 ? v : (v < 30 ? v - 19 : v - 16);
}

// acc[p] += sum_k w[k] * win[k+p]
__device__ __forceinline__ void taps(const float* win, const float* __restrict__ w,
                                     float acc[8]) {
#pragma unroll
    for (int k = 0; k < NTAP; ++k) {
        float wk = w[k];
#pragma unroll
        for (int p = 0; p < 8; ++p) acc[p] = fmaf(wk, win[k + p], acc[p]);
    }
}

// ---- prep: padded val/cls volumes. guards: val=0, cls=255 ----
__global__ __launch_bounds__(256) void kprep2(const int* __restrict__ x,
                                              const float* __restrict__ noise,
                                              const float* __restrict__ mus,
                                              const float* __restrict__ stds,
                                              float* __restrict__ vp,
                                              unsigned char* __restrict__ cp) {
    int z = blockIdx.y;
    int idx = blockIdx.x * 256 + threadIdx.x;  // 0..28159 (= HH*PW)
    int y = idx / PW, xp = idx - y * PW;
    long long po = (long long)z * HH * PW + idx;
    int gx = xp - PADC;
    if ((unsigned)gx < (unsigned)WW) {
        long long gi = (long long)z * ZSTR + (long long)y * WW + gx;
        int c = lutmap(x[gi]);
        vp[po] = mus[c] + stds[c] * noise[(long long)c * NV + gi];
        cp[po] = (unsigned char)c;
    } else {
        vp[po] = 0.f;
        cp[po] = (unsigned char)255;
    }
}

// ---- pad-copy d_out (summed volume) into padded layout for final smooth ----
__global__ __launch_bounds__(256) void kpad(const float* __restrict__ src,
                                            float* __restrict__ vp) {
    int z = blockIdx.y;
    int idx = blockIdx.x * 256 + threadIdx.x;
    int y = idx / PW, xp = idx - y * PW;
    long long po = (long long)z * HH * PW + idx;
    int gx = xp - PADC;
    vp[po] = ((unsigned)gx < (unsigned)WW)
                 ? src[(long long)z * ZSTR + (long long)y * WW + gx]
                 : 0.f;
}

// ---- weights: wts[c][0..40], c=20 is final sigma ----
__global__ void kweights(const float* __restrict__ gsig, const float* __restrict__ fsig,
                         float* __restrict__ wts) {
    int c = threadIdx.x;
    if (c > 20) return;
    float sigma = (c < 20) ? gsig[c] : fsig[0];
    float inv = 1.0f / sigma;
    float buf[NTAP];
    float s = 0.f;
    for (int k = 0; k < NTAP; ++k) {
        float d = (float)(k - RAD) * inv;
        buf[k] = expf(-0.5f * d * d);
        s += buf[k];
    }
    float r = 1.0f / s;
    for (int k = 0; k < NTAP; ++k) wts[c * NTAP + k] = buf[k] * r;
}

// ---- fused X+Y smooth v2: conv-x windows direct from padded global,
//      LDS holds only conv-x output A2[208][33] (y in -24..183), 1 barrier ----
template <bool MASKED>
__global__ __launch_bounds__(256, 4) void ksmooth_xy2(const float* __restrict__ vp,
                                                      const unsigned char* __restrict__ cp,
                                                      const float* __restrict__ wts,
                                                      float* __restrict__ dst, int c0) {
    __shared__ float A2[208][33];

    const int cls_i = MASKED ? (c0 + (int)blockIdx.x) : 20;
    const int x0 = (int)blockIdx.y * 32;
    const int z = blockIdx.z;
    const float* __restrict__ w = wts + cls_i * NTAP;
    const int tid = threadIdx.x;

    // zero y-halo rows (0..23, 184..207); conv-x fills 24..183 — disjoint
    for (int i = tid; i < 48 * 32; i += 256) {
        int r = i >> 5, xx = i & 31;
        A2[(r < 24) ? r : (160 + r)][xx] = 0.f;
    }

    const long long zb = (long long)z * HH * PW;
    const int m = tid & 3, q = tid >> 2, xb = m * 8;
#pragma unroll
    for (int pass = 0; pass < 3; ++pass) {
        int y = pass * 64 + q;
        if (y < HH) {
            // window start padded col: (x0+xb-20)+24 = x0+xb+4 (16B aligned)
            const float* srcp = vp + zb + (long long)y * PW + (x0 + xb + 4);
            float win[48];
            if (MASKED) {
                const unsigned* cu =
                    (const unsigned*)(cp + zb + (long long)y * PW + (x0 + xb + 4));
                const unsigned cb = (unsigned)cls_i;
#pragma unroll
                for (int i = 0; i < 12; ++i) {
                    float4 v4 = ((const float4*)srcp)[i];
                    unsigned u = cu[i];
                    win[4 * i + 0] = ((u & 0xffu) == cb) ? v4.x : 0.f;
                    win[4 * i + 1] = (((u >> 8) & 0xffu) == cb) ? v4.y : 0.f;
                    win[4 * i + 2] = (((u >> 16) & 0xffu) == cb) ? v4.z : 0.f;
                    win[4 * i + 3] = ((u >> 24) == cb) ? v4.w : 0.f;
                }
            } else {
#pragma unroll
                for (int i = 0; i < 12; ++i) {
                    float4 v4 = ((const float4*)srcp)[i];
                    win[4 * i + 0] = v4.x;
                    win[4 * i + 1] = v4.y;
                    win[4 * i + 2] = v4.z;
                    win[4 * i + 3] = v4.w;
                }
            }
            float acc[8] = {0, 0, 0, 0, 0, 0, 0, 0};
            taps(win, w, acc);
#pragma unroll
            for (int p = 0; p < 8; ++p) A2[24 + y][xb + p] = acc[p];
        }
    }
    __syncthreads();

    // conv-y from A2 (zero halos already in place), write to global
    const int x = tid & 31, yg = tid >> 5;
    const long long obase =
        (MASKED ? ((long long)blockIdx.x * DD + z) : (long long)z) * ZSTR;
#pragma unroll
    for (int pass = 0; pass < 3; ++pass) {
        int yb = pass * 64 + yg * 8;
        if (yb < HH) {
            float win[48];
#pragma unroll
            for (int j = 0; j < 48; ++j) win[j] = A2[yb + 4 + j][x];
            float acc[8] = {0, 0, 0, 0, 0, 0, 0, 0};
            taps(win, w, acc);
#pragma unroll
            for (int p = 0; p < 8; ++p)
                dst[obase + (long long)(yb + p) * WW + x0 + x] = acc[p];
        }
    }
}

// ---- Z smooth; accumulates over nc classes (unchanged this round) ----
template <bool ACCUM>
__global__ __launch_bounds__(256) void ksmooth_z(const float* __restrict__ src,
                                                 const float* __restrict__ wts,
                                                 float* __restrict__ out, int c0,
                                                 int nc) {
    constexpr int LW = 33;
    __shared__ float L[104 * LW];

    const int x0 = blockIdx.x * 32;
    const int z0 = blockIdx.y * 64;
    const int y = blockIdx.z;
    const int x = threadIdx.x & 31;
    const int tg = threadIdx.x >> 5;

    float acc[8] = {0, 0, 0, 0, 0, 0, 0, 0};
    for (int cc = 0; cc < nc; ++cc) {
        const float* w = wts + (ACCUM ? (c0 + cc) : 20) * NTAP;
        const float* sv = src + (long long)cc * NV;
        for (int t = tg; t < 104; t += 8) {
            int gz = z0 - RAD + t;
            float v = ((unsigned)gz < (unsigned)DD)
                          ? sv[(long long)gz * ZSTR + (long long)y * WW + x0 + x]
                          : 0.f;
            L[t * LW + x] = v;
        }
        __syncthreads();
        {
            const int zb2 = tg * 8;
            float win[48];
#pragma unroll
            for (int j = 0; j < 48; ++j) win[j] = L[(zb2 + j) * LW + x];
            taps(win, w, acc);
        }
        __syncthreads();
    }
    const int zb2 = tg * 8;
#pragma unroll
    for (int p = 0; p < 8; ++p) {
        long long o = (long long)(z0 + zb2 + p) * ZSTR + (long long)y * WW + x0 + x;
        if (ACCUM)
            out[o] += acc[p];
        else
            out[o] = acc[p];
    }
}

extern "C" void kernel_launch(void* const* d_in, const int* in_sizes, int n_in,
                              void* d_out, int out_size, void* d_ws, size_t ws_size,
                              hipStream_t stream) {
    const int* x = (const int*)d_in[0];
    const float* noise = (const float*)d_in[1];
    const float* mus = (const float*)d_in[2];
    const float* stds = (const float*)d_in[3];
    const float* gsig = (const float*)d_in[4];
    const float* fsig = (const float*)d_in[5];
    float* out = (float*)d_out;

    char* ws = (char*)d_ws;
    size_t off = 0;
    float* wts = (float*)(ws + off);
    off += 4096;
    float* vp = (float*)(ws + off);
    off += (size_t)(NVP * 4);          // padded val
    unsigned char* cpv = (unsigned char*)(ws + off);
    off += (size_t)NVP;                // padded cls (NVP % 256 == 0)
    float* xy = (float*)(ws + off);    // C per-class conv-xy volumes
    float* ftmp = xy;                  // reused after all class chunks done

    long long cap = ((long long)ws_size - (long long)off) / VOLB;
    int C = cap < 1 ? 1 : (cap > 20 ? 20 : (int)cap);

    kweights<<<1, 64, 0, stream>>>(gsig, fsig, wts);
    kprep2<<<dim3(HH * PW / 256, DD), 256, 0, stream>>>(x, noise, mus, stds, vp, cpv);
    hipMemsetAsync(d_out, 0, (size_t)VOLB, stream);

    for (int c0 = 0; c0 < 20; c0 += C) {
        int cc = (20 - c0) < C ? (20 - c0) : C;
        // class-fastest grid: 20 blocks sharing a (x-tile,z) window run adjacently → L2 hits
        ksmooth_xy2<true><<<dim3(cc, 4, DD), 256, 0, stream>>>(vp, cpv, wts, xy, c0);
        ksmooth_z<true><<<dim3(4, 2, HH), 256, 0, stream>>>(xy, wts, out, c0, cc);
    }
    // final smooth: out -> pad -> XY -> ftmp -> Z -> out
    kpad<<<dim3(HH * PW / 256, DD), 256, 0, stream>>>(out, vp);
    ksmooth_xy2<false><<<dim3(1, 4, DD), 256, 0, stream>>>(vp, cpv, wts, ftmp, 0);
    ksmooth_z<false><<<dim3(4, 2, HH), 256, 0, stream>>>(ftmp, wts, out, 0, 1);
}

// Round 8
// 535.136 us; speedup vs baseline: 1.7461x; 1.0696x over previous
//
#include <hip/hip_runtime.h>

// Volume geometry (static per reference): [D=128, H=160, W=128], fp32
constexpr int DD = 128, HH = 160, WW = 128;
constexpr int ZSTR = HH * WW;              // 20480
constexpr long long NV = (long long)DD * HH * WW;   // 2621440
constexpr long long VOLB = NV * 4;         // 10485760 bytes
constexpr int RAD = 20, NTAP = 41;
// x-padded layout: [z][y][xp], xp = 24 zero | 128 data | 24 zero
constexpr int PW = 176;
constexpr int PADC = 24;
constexpr long long NVP = (long long)DD * HH * PW;  // 3604480

__device__ __forceinline__ int lutmap(int v) {
    // LUT = [0..19] + [1..10, 14..19]
    return v < 20 ? v : (v < 30 ? v - 19 : v - 16);
}

// acc[p] += sum_k w[k] * win[k+p]
__device__ __forceinline__ void taps(const float* win, const float* __restrict__ w,
                                     float acc[8]) {
#pragma unroll
    for (int k = 0; k < NTAP; ++k) {
        float wk = w[k];
#pragma unroll
        for (int p = 0; p < 8; ++p) acc[p] = fmaf(wk, win[k + p], acc[p]);
    }
}

// ---- prep: padded val/cls volumes. guards: val=0, cls=255 ----
__global__ __launch_bounds__(256) void kprep2(const int* __restrict__ x,
                                              const float* __restrict__ noise,
                                              const float* __restrict__ mus,
                                              const float* __restrict__ stds,
                                              float* __restrict__ vp,
                                              unsigned char* __restrict__ cp) {
    int z = blockIdx.y;
    int idx = blockIdx.x * 256 + threadIdx.x;  // 0..28159 (= HH*PW)
    int y = idx / PW, xp = idx - y * PW;
    long long po = (long long)z * HH * PW + idx;
    int gx = xp - PADC;
    if ((unsigned)gx < (unsigned)WW) {
        long long gi = (long long)z * ZSTR + (long long)y * WW + gx;
        int c = lutmap(x[gi]);
        vp[po] = mus[c] + stds[c] * noise[(long long)c * NV + gi];
        cp[po] = (unsigned char)c;
    } else {
        vp[po] = 0.f;
        cp[po] = (unsigned char)255;
    }
}

// ---- pad-copy d_out (summed volume) into padded layout for final smooth ----
__global__ __launch_bounds__(256) void kpad(const float* __restrict__ src,
                                            float* __restrict__ vp) {
    int z = blockIdx.y;
    int idx = blockIdx.x * 256 + threadIdx.x;
    int y = idx / PW, xp = idx - y * PW;
    long long po = (long long)z * HH * PW + idx;
    int gx = xp - PADC;
    vp[po] = ((unsigned)gx < (unsigned)WW)
                 ? src[(long long)z * ZSTR + (long long)y * WW + gx]
                 : 0.f;
}

// ---- weights: wts[c][0..40], c=20 is final sigma ----
__global__ void kweights(const float* __restrict__ gsig, const float* __restrict__ fsig,
                         float* __restrict__ wts) {
    int c = threadIdx.x;
    if (c > 20) return;
    float sigma = (c < 20) ? gsig[c] : fsig[0];
    float inv = 1.0f / sigma;
    float buf[NTAP];
    float s = 0.f;
    for (int k = 0; k < NTAP; ++k) {
        float d = (float)(k - RAD) * inv;
        buf[k] = expf(-0.5f * d * d);
        s += buf[k];
    }
    float r = 1.0f / s;
    for (int k = 0; k < NTAP; ++k) wts[c * NTAP + k] = buf[k] * r;
}

// ---- fused X+Y smooth v2 (unchanged from round 5's measured version) ----
template <bool MASKED>
__global__ __launch_bounds__(256, 4) void ksmooth_xy2(const float* __restrict__ vp,
                                                      const unsigned char* __restrict__ cp,
                                                      const float* __restrict__ wts,
                                                      float* __restrict__ dst, int c0) {
    __shared__ float A2[208][33];

    const int cls_i = MASKED ? (c0 + (int)blockIdx.x) : 20;
    const int x0 = (int)blockIdx.y * 32;
    const int z = blockIdx.z;
    const float* __restrict__ w = wts + cls_i * NTAP;
    const int tid = threadIdx.x;

    // zero y-halo rows (0..23, 184..207); conv-x fills 24..183 — disjoint
    for (int i = tid; i < 48 * 32; i += 256) {
        int r = i >> 5, xx = i & 31;
        A2[(r < 24) ? r : (160 + r)][xx] = 0.f;
    }

    const long long zb = (long long)z * HH * PW;
    const int m = tid & 3, q = tid >> 2, xb = m * 8;
#pragma unroll
    for (int pass = 0; pass < 3; ++pass) {
        int y = pass * 64 + q;
        if (y < HH) {
            // window start padded col: (x0+xb-20)+24 = x0+xb+4 (16B aligned)
            const float* srcp = vp + zb + (long long)y * PW + (x0 + xb + 4);
            float win[48];
            if (MASKED) {
                const unsigned* cu =
                    (const unsigned*)(cp + zb + (long long)y * PW + (x0 + xb + 4));
                const unsigned cb = (unsigned)cls_i;
#pragma unroll
                for (int i = 0; i < 12; ++i) {
                    float4 v4 = ((const float4*)srcp)[i];
                    unsigned u = cu[i];
                    win[4 * i + 0] = ((u & 0xffu) == cb) ? v4.x : 0.f;
                    win[4 * i + 1] = (((u >> 8) & 0xffu) == cb) ? v4.y : 0.f;
                    win[4 * i + 2] = (((u >> 16) & 0xffu) == cb) ? v4.z : 0.f;
                    win[4 * i + 3] = ((u >> 24) == cb) ? v4.w : 0.f;
                }
            } else {
#pragma unroll
                for (int i = 0; i < 12; ++i) {
                    float4 v4 = ((const float4*)srcp)[i];
                    win[4 * i + 0] = v4.x;
                    win[4 * i + 1] = v4.y;
                    win[4 * i + 2] = v4.z;
                    win[4 * i + 3] = v4.w;
                }
            }
            float acc[8] = {0, 0, 0, 0, 0, 0, 0, 0};
            taps(win, w, acc);
#pragma unroll
            for (int p = 0; p < 8; ++p) A2[24 + y][xb + p] = acc[p];
        }
    }
    __syncthreads();

    // conv-y from A2 (zero halos already in place), write to global
    const int x = tid & 31, yg = tid >> 5;
    const long long obase =
        (MASKED ? ((long long)blockIdx.x * DD + z) : (long long)z) * ZSTR;
#pragma unroll
    for (int pass = 0; pass < 3; ++pass) {
        int yb = pass * 64 + yg * 8;
        if (yb < HH) {
            float win[48];
#pragma unroll
            for (int j = 0; j < 48; ++j) win[j] = A2[yb + 4 + j][x];
            float acc[8] = {0, 0, 0, 0, 0, 0, 0, 0};
            taps(win, w, acc);
#pragma unroll
            for (int p = 0; p < 8; ++p)
                dst[obase + (long long)(yb + p) * WW + x0 + x] = acc[p];
        }
    }
}

// ---- Z smooth v3: full-z column tile (16x × 128z × 1y), ping-pong LDS,
//      one barrier per class, class-sum accumulated in registers ----
// LDS rows: 0..19 zero | 20..147 = z 0..127 | 148..167 zero (zeroed once).
template <bool ACCUM>
__global__ __launch_bounds__(256) void ksmooth_z3(const float* __restrict__ src,
                                                  const float* __restrict__ wts,
                                                  float* __restrict__ out, int c0,
                                                  int nc) {
    __shared__ float L[2][168][17];

    const int x0 = (int)blockIdx.x * 16;
    const int y = (int)blockIdx.y;
    const int tid = threadIdx.x;
    // staging mapping: 2 float4 rows per thread
    const int sxq = tid & 3;   // float4 column (4 floats)
    const int szr = tid >> 2;  // z row 0..63 (and +64)
    // compute mapping: 16 groups × 8 z-outputs
    const int cx = tid & 15;
    const int tg = tid >> 4;
    const int zb = tg * 8;

    const long long colbase = (long long)y * WW + x0;
    const long long sgoff = colbase + sxq * 4;

    // zero z-halo rows of both buffers (data cols 0..15)
    for (int i = tid; i < 2 * 40 * 16; i += 256) {
        int b = i / 640;
        int rem = i - b * 640;
        int r = rem >> 4, col = rem & 15;
        L[b][(r < 20) ? r : (128 + r)][col] = 0.f;
    }

    // prefetch class 0 and stage into buffer 0
    {
        const float4 va = *(const float4*)(src + (long long)szr * ZSTR + sgoff);
        const float4 vb = *(const float4*)(src + (long long)(szr + 64) * ZSTR + sgoff);
        const int wc = sxq * 4;
        L[0][20 + szr][wc + 0] = va.x;
        L[0][20 + szr][wc + 1] = va.y;
        L[0][20 + szr][wc + 2] = va.z;
        L[0][20 + szr][wc + 3] = va.w;
        L[0][84 + szr][wc + 0] = vb.x;
        L[0][84 + szr][wc + 1] = vb.y;
        L[0][84 + szr][wc + 2] = vb.z;
        L[0][84 + szr][wc + 3] = vb.w;
    }
    __syncthreads();

    float acc[8] = {0, 0, 0, 0, 0, 0, 0, 0};
    for (int cc = 0; cc < nc; ++cc) {
        const int cur = cc & 1;
        const bool more = (cc + 1 < nc);
        float4 na, nb;
        if (more) {
            const float* sv = src + (long long)(cc + 1) * NV;
            na = *(const float4*)(sv + (long long)szr * ZSTR + sgoff);
            nb = *(const float4*)(sv + (long long)(szr + 64) * ZSTR + sgoff);
        }
        // compute class cc from L[cur]
        {
            const float* w = wts + (ACCUM ? (c0 + cc) : 20) * NTAP;
            float win[48];
#pragma unroll
            for (int j = 0; j < 48; ++j) win[j] = L[cur][zb + j][cx];
            taps(win, w, acc);
        }
        if (more) {
            const int nxt = cur ^ 1;
            const int wc = sxq * 4;
            L[nxt][20 + szr][wc + 0] = na.x;
            L[nxt][20 + szr][wc + 1] = na.y;
            L[nxt][20 + szr][wc + 2] = na.z;
            L[nxt][20 + szr][wc + 3] = na.w;
            L[nxt][84 + szr][wc + 0] = nb.x;
            L[nxt][84 + szr][wc + 1] = nb.y;
            L[nxt][84 + szr][wc + 2] = nb.z;
            L[nxt][84 + szr][wc + 3] = nb.w;
        }
        __syncthreads();
    }

#pragma unroll
    for (int p = 0; p < 8; ++p) {
        long long o = (long long)(zb + p) * ZSTR + colbase + cx;
        if (ACCUM)
            out[o] += acc[p];
        else
            out[o] = acc[p];
    }
}

extern "C" void kernel_launch(void* const* d_in, const int* in_sizes, int n_in,
                              void* d_out, int out_size, void* d_ws, size_t ws_size,
                              hipStream_t stream) {
    const int* x = (const int*)d_in[0];
    const float* noise = (const float*)d_in[1];
    const float* mus = (const float*)d_in[2];
    const float* stds = (const float*)d_in[3];
    const float* gsig = (const float*)d_in[4];
    const float* fsig = (const float*)d_in[5];
    float* out = (float*)d_out;

    char* ws = (char*)d_ws;
    size_t off = 0;
    float* wts = (float*)(ws + off);
    off += 4096;
    float* vp = (float*)(ws + off);
    off += (size_t)(NVP * 4);          // padded val
    unsigned char* cpv = (unsigned char*)(ws + off);
    off += (size_t)NVP;                // padded cls (NVP % 256 == 0)
    float* xy = (float*)(ws + off);    // C per-class conv-xy volumes
    float* ftmp = xy;                  // reused after all class chunks done

    long long cap = ((long long)ws_size - (long long)off) / VOLB;
    int C = cap < 1 ? 1 : (cap > 20 ? 20 : (int)cap);

    kweights<<<1, 64, 0, stream>>>(gsig, fsig, wts);
    kprep2<<<dim3(HH * PW / 256, DD), 256, 0, stream>>>(x, noise, mus, stds, vp, cpv);
    hipMemsetAsync(d_out, 0, (size_t)VOLB, stream);

    for (int c0 = 0; c0 < 20; c0 += C) {
        int cc = (20 - c0) < C ? (20 - c0) : C;
        // class-fastest grid: 20 blocks sharing a (x-tile,z) window run adjacently → L2 hits
        ksmooth_xy2<true><<<dim3(cc, 4, DD), 256, 0, stream>>>(vp, cpv, wts, xy, c0);
        ksmooth_z3<true><<<dim3(WW / 16, HH), 256, 0, stream>>>(xy, wts, out, c0, cc);
    }
    // final smooth: out -> pad -> XY -> ftmp -> Z -> out
    kpad<<<dim3(HH * PW / 256, DD), 256, 0, stream>>>(out, vp);
    ksmooth_xy2<false><<<dim3(1, 4, DD), 256, 0, stream>>>(vp, cpv, wts, ftmp, 0);
    ksmooth_z3<false><<<dim3(WW / 16, HH), 256, 0, stream>>>(ftmp, wts, out, 0, 1);
}

// Round 9
// 524.302 us; speedup vs baseline: 1.7822x; 1.0207x over previous
//
#include <hip/hip_runtime.h>

// Volume geometry (static per reference): [D=128, H=160, W=128], fp32
constexpr int DD = 128, HH = 160, WW = 128;
constexpr int ZSTR = HH * WW;              // 20480
constexpr long long NV = (long long)DD * HH * WW;   // 2621440
constexpr long long VOLB = NV * 4;         // 10485760 bytes
constexpr int RAD = 20, NTAP = 41;
// x-padded layout: [z][y][xp], xp = 24 zero | 128 data | 24 zero
constexpr int PW = 176;
constexpr int PADC = 24;
constexpr long long NVP = (long long)DD * HH * PW;  // 3604480
constexpr int PV4 = HH * PW / 4;           // 7040 float4 per z-plane

__device__ __forceinline__ int lutmap(int v) {
    // LUT = [0..19] + [1..10, 14..19]
    return v < 20 ? v : (v < 30 ? v - 19 : v - 16);
}

// acc[p] += sum_k w[k] * win[k+p]
__device__ __forceinline__ void taps(const float* win, const float* __restrict__ w,
                                     float acc[8]) {
#pragma unroll
    for (int k = 0; k < NTAP; ++k) {
        float wk = w[k];
#pragma unroll
        for (int p = 0; p < 8; ++p) acc[p] = fmaf(wk, win[k + p], acc[p]);
    }
}

// ---- prep v2 (4x vectorized): padded val/cls. guards: val=0, cls=255 ----
// 4-aligned col groups are homogeneous (guard cols 0..23,152..175; data 24..151).
__global__ __launch_bounds__(256) void kprep2v(const int* __restrict__ x,
                                               const float* __restrict__ noise,
                                               const float* __restrict__ mus,
                                               const float* __restrict__ stds,
                                               float* __restrict__ vp,
                                               unsigned* __restrict__ cp4) {
    const int z = blockIdx.y;
    const int t = blockIdx.x * 256 + threadIdx.x;  // float4 index within plane
    if (t >= PV4) return;
    const int col4 = t * 4;
    const int y = col4 / PW;
    const int xp = col4 - y * PW;
    const long long o4 = (long long)z * PV4 + t;
    const int gx = xp - PADC;
    float4 v;
    unsigned cw;
    if ((unsigned)gx < (unsigned)WW) {
        const long long gi = (long long)z * ZSTR + (long long)y * WW + gx;
        const int4 xv = *(const int4*)(x + gi);
        const int c0 = lutmap(xv.x), c1 = lutmap(xv.y), c2 = lutmap(xv.z),
                  c3 = lutmap(xv.w);
        v.x = mus[c0] + stds[c0] * noise[(long long)c0 * NV + gi];
        v.y = mus[c1] + stds[c1] * noise[(long long)c1 * NV + gi + 1];
        v.z = mus[c2] + stds[c2] * noise[(long long)c2 * NV + gi + 2];
        v.w = mus[c3] + stds[c3] * noise[(long long)c3 * NV + gi + 3];
        cw = (unsigned)c0 | ((unsigned)c1 << 8) | ((unsigned)c2 << 16) |
             ((unsigned)c3 << 24);
    } else {
        v = make_float4(0.f, 0.f, 0.f, 0.f);
        cw = 0xFFFFFFFFu;
    }
    ((float4*)vp)[o4] = v;
    cp4[o4] = cw;
}

// ---- pad-copy d_out (summed, std layout) into padded layout (slow path) ----
__global__ __launch_bounds__(256) void kpad(const float* __restrict__ src,
                                            float* __restrict__ vp) {
    int z = blockIdx.y;
    int idx = blockIdx.x * 256 + threadIdx.x;
    int y = idx / PW, xp = idx - y * PW;
    long long po = (long long)z * HH * PW + idx;
    int gx = xp - PADC;
    vp[po] = ((unsigned)gx < (unsigned)WW)
                 ? src[(long long)z * ZSTR + (long long)y * WW + gx]
                 : 0.f;
}

// ---- weights: wts[c][0..40], c=20 is final sigma ----
__global__ void kweights(const float* __restrict__ gsig, const float* __restrict__ fsig,
                         float* __restrict__ wts) {
    int c = threadIdx.x;
    if (c > 20) return;
    float sigma = (c < 20) ? gsig[c] : fsig[0];
    float inv = 1.0f / sigma;
    float buf[NTAP];
    float s = 0.f;
    for (int k = 0; k < NTAP; ++k) {
        float d = (float)(k - RAD) * inv;
        buf[k] = expf(-0.5f * d * d);
        s += buf[k];
    }
    float r = 1.0f / s;
    for (int k = 0; k < NTAP; ++k) wts[c * NTAP + k] = buf[k] * r;
}

// ---- fused X+Y smooth v2. Compute identical to round-5 measured version.
//      ONLY change: dst layout is transposed [vol][y][z][x] for z-pass locality.
template <bool MASKED>
__global__ __launch_bounds__(256, 4) void ksmooth_xy2(const float* __restrict__ vp,
                                                      const unsigned char* __restrict__ cp,
                                                      const float* __restrict__ wts,
                                                      float* __restrict__ dst, int c0) {
    __shared__ float A2[208][33];

    const int cls_i = MASKED ? (c0 + (int)blockIdx.x) : 20;
    const int x0 = (int)blockIdx.y * 32;
    const int z = blockIdx.z;
    const float* __restrict__ w = wts + cls_i * NTAP;
    const int tid = threadIdx.x;

    // zero y-halo rows (0..23, 184..207); conv-x fills 24..183 — disjoint
    for (int i = tid; i < 48 * 32; i += 256) {
        int r = i >> 5, xx = i & 31;
        A2[(r < 24) ? r : (160 + r)][xx] = 0.f;
    }

    const long long zb = (long long)z * HH * PW;
    const int m = tid & 3, q = tid >> 2, xb = m * 8;
#pragma unroll
    for (int pass = 0; pass < 3; ++pass) {
        int y = pass * 64 + q;
        if (y < HH) {
            // window start padded col: (x0+xb-20)+24 = x0+xb+4 (16B aligned)
            const float* srcp = vp + zb + (long long)y * PW + (x0 + xb + 4);
            float win[48];
            if (MASKED) {
                const unsigned* cu =
                    (const unsigned*)(cp + zb + (long long)y * PW + (x0 + xb + 4));
                const unsigned cb = (unsigned)cls_i;
#pragma unroll
                for (int i = 0; i < 12; ++i) {
                    float4 v4 = ((const float4*)srcp)[i];
                    unsigned u = cu[i];
                    win[4 * i + 0] = ((u & 0xffu) == cb) ? v4.x : 0.f;
                    win[4 * i + 1] = (((u >> 8) & 0xffu) == cb) ? v4.y : 0.f;
                    win[4 * i + 2] = (((u >> 16) & 0xffu) == cb) ? v4.z : 0.f;
                    win[4 * i + 3] = ((u >> 24) == cb) ? v4.w : 0.f;
                }
            } else {
#pragma unroll
                for (int i = 0; i < 12; ++i) {
                    float4 v4 = ((const float4*)srcp)[i];
                    win[4 * i + 0] = v4.x;
                    win[4 * i + 1] = v4.y;
                    win[4 * i + 2] = v4.z;
                    win[4 * i + 3] = v4.w;
                }
            }
            float acc[8] = {0, 0, 0, 0, 0, 0, 0, 0};
            taps(win, w, acc);
#pragma unroll
            for (int p = 0; p < 8; ++p) A2[24 + y][xb + p] = acc[p];
        }
    }
    __syncthreads();

    // conv-y from A2, write TRANSPOSED: dst[vol][y][z][x]
    const int x = tid & 31, yg = tid >> 5;
    const long long vbase = MASKED ? ((long long)blockIdx.x * HH) : 0LL;
#pragma unroll
    for (int pass = 0; pass < 3; ++pass) {
        int yb = pass * 64 + yg * 8;
        if (yb < HH) {
            float win[48];
#pragma unroll
            for (int j = 0; j < 48; ++j) win[j] = A2[yb + 4 + j][x];
            float acc[8] = {0, 0, 0, 0, 0, 0, 0, 0};
            taps(win, w, acc);
#pragma unroll
            for (int p = 0; p < 8; ++p)
                dst[((vbase + yb + p) * DD + z) * WW + x0 + x] = acc[p];
        }
    }
}

// ---- Z smooth v4: reads transposed [vol][y][z][x] (512B-stride rows),
//      full-z column tile, ping-pong LDS, 1 barrier/class, reg accumulation.
// MODE 0: store class-sum into PADDED buffer (fast path, nc=20)
// MODE 1: store into standard-layout out (final smooth, nc=1, final weights)
// MODE 2: accumulate (+=) into standard-layout out (slow path chunks)
template <int MODE>
__global__ __launch_bounds__(256) void ksmooth_z4(const float* __restrict__ src,
                                                  const float* __restrict__ wts,
                                                  float* __restrict__ out, int c0,
                                                  int nc) {
    __shared__ float L[2][168][17];

    const int x0 = (int)blockIdx.x * 16;
    const int y = (int)blockIdx.y;
    const int tid = threadIdx.x;
    // staging mapping: 2 float4 rows per thread
    const int sxq = tid & 3;   // float4 column (4 floats)
    const int szr = tid >> 2;  // z row 0..63 (and +64)
    // compute mapping: 16 groups × 8 z-outputs
    const int cx = tid & 15;
    const int tg = tid >> 4;
    const int zb = tg * 8;

    // transposed source: row z of this (vol,y) starts at ((vol*HH+y)*DD+z)*WW
    const long long ybase = (long long)y * DD * WW + x0 + sxq * 4;

    // zero z-halo rows of both buffers (data cols 0..15)
    for (int i = tid; i < 2 * 40 * 16; i += 256) {
        int b = i / 640;
        int rem = i - b * 640;
        int r = rem >> 4, col = rem & 15;
        L[b][(r < 20) ? r : (128 + r)][col] = 0.f;
    }

    // prefetch class 0 and stage into buffer 0
    {
        const float4 va = *(const float4*)(src + ybase + (long long)szr * WW);
        const float4 vb = *(const float4*)(src + ybase + (long long)(szr + 64) * WW);
        const int wc = sxq * 4;
        L[0][20 + szr][wc + 0] = va.x;
        L[0][20 + szr][wc + 1] = va.y;
        L[0][20 + szr][wc + 2] = va.z;
        L[0][20 + szr][wc + 3] = va.w;
        L[0][84 + szr][wc + 0] = vb.x;
        L[0][84 + szr][wc + 1] = vb.y;
        L[0][84 + szr][wc + 2] = vb.z;
        L[0][84 + szr][wc + 3] = vb.w;
    }
    __syncthreads();

    float acc[8] = {0, 0, 0, 0, 0, 0, 0, 0};
    for (int cc = 0; cc < nc; ++cc) {
        const int cur = cc & 1;
        const bool more = (cc + 1 < nc);
        float4 na, nb;
        if (more) {
            const float* sv = src + (long long)(cc + 1) * NV;
            na = *(const float4*)(sv + ybase + (long long)szr * WW);
            nb = *(const float4*)(sv + ybase + (long long)(szr + 64) * WW);
        }
        // compute class cc from L[cur]
        {
            const float* w = wts + ((MODE == 1) ? 20 : (c0 + cc)) * NTAP;
            float win[48];
#pragma unroll
            for (int j = 0; j < 48; ++j) win[j] = L[cur][zb + j][cx];
            taps(win, w, acc);
        }
        if (more) {
            const int nxt = cur ^ 1;
            const int wc = sxq * 4;
            L[nxt][20 + szr][wc + 0] = na.x;
            L[nxt][20 + szr][wc + 1] = na.y;
            L[nxt][20 + szr][wc + 2] = na.z;
            L[nxt][20 + szr][wc + 3] = na.w;
            L[nxt][84 + szr][wc + 0] = nb.x;
            L[nxt][84 + szr][wc + 1] = nb.y;
            L[nxt][84 + szr][wc + 2] = nb.z;
            L[nxt][84 + szr][wc + 3] = nb.w;
        }
        __syncthreads();
    }

#pragma unroll
    for (int p = 0; p < 8; ++p) {
        const int zo = zb + p;
        if (MODE == 0) {
            // padded standard layout [z][y][xp]
            out[(long long)zo * HH * PW + (long long)y * PW + PADC + x0 + cx] = acc[p];
        } else {
            long long o = (long long)zo * ZSTR + (long long)y * WW + x0 + cx;
            if (MODE == 2)
                out[o] += acc[p];
            else
                out[o] = acc[p];
        }
    }
}

extern "C" void kernel_launch(void* const* d_in, const int* in_sizes, int n_in,
                              void* d_out, int out_size, void* d_ws, size_t ws_size,
                              hipStream_t stream) {
    const int* x = (const int*)d_in[0];
    const float* noise = (const float*)d_in[1];
    const float* mus = (const float*)d_in[2];
    const float* stds = (const float*)d_in[3];
    const float* gsig = (const float*)d_in[4];
    const float* fsig = (const float*)d_in[5];
    float* out = (float*)d_out;

    char* ws = (char*)d_ws;
    size_t off = 0;
    float* wts = (float*)(ws + off);
    off += 4096;
    float* vp = (float*)(ws + off);
    off += (size_t)(NVP * 4);          // padded val (fast path: reused for sum)
    unsigned char* cpv = (unsigned char*)(ws + off);
    off += (size_t)NVP;                // padded cls (NVP % 256 == 0)
    float* ftmp = (float*)(ws + off);
    off += (size_t)VOLB;               // final-smooth xy intermediate
    float* xy = (float*)(ws + off);    // C per-class conv-xy volumes (transposed)

    long long cap = ((long long)ws_size - (long long)off) / VOLB;
    int C = cap < 1 ? 1 : (cap > 20 ? 20 : (int)cap);

    kweights<<<1, 64, 0, stream>>>(gsig, fsig, wts);
    kprep2v<<<dim3((PV4 + 255) / 256, DD), 256, 0, stream>>>(x, noise, mus, stds, vp,
                                                             (unsigned*)cpv);

    if (C >= 20) {
        // fast path: single chunk; class-sum stored straight into vp (padded);
        // val data in vp is dead after xy2t, guards stay zero from prep.
        ksmooth_xy2<true><<<dim3(20, 4, DD), 256, 0, stream>>>(vp, cpv, wts, xy, 0);
        ksmooth_z4<0><<<dim3(WW / 16, HH), 256, 0, stream>>>(xy, wts, vp, 0, 20);
        ksmooth_xy2<false><<<dim3(1, 4, DD), 256, 0, stream>>>(vp, cpv, wts, ftmp, 0);
        ksmooth_z4<1><<<dim3(WW / 16, HH), 256, 0, stream>>>(ftmp, wts, out, 0, 1);
    } else {
        hipMemsetAsync(d_out, 0, (size_t)VOLB, stream);
        for (int c0 = 0; c0 < 20; c0 += C) {
            int cc = (20 - c0) < C ? (20 - c0) : C;
            ksmooth_xy2<true><<<dim3(cc, 4, DD), 256, 0, stream>>>(vp, cpv, wts, xy, c0);
            ksmooth_z4<2><<<dim3(WW / 16, HH), 256, 0, stream>>>(xy, wts, out, c0, cc);
        }
        kpad<<<dim3(HH * PW / 256, DD), 256, 0, stream>>>(out, vp);
        ksmooth_xy2<false><<<dim3(1, 4, DD), 256, 0, stream>>>(vp, cpv, wts, ftmp, 0);
        ksmooth_z4<1><<<dim3(WW / 16, HH), 256, 0, stream>>>(ftmp, wts, out, 0, 1);
    }
}